// Round 1
// baseline (15.727 us; speedup 1.0000x reference)
//
#include <hip/hip_runtime.h>

// DepthLoss: loss = mean over {d>0} of |img[b,0,r,c] - d|, single f32 scalar out.
// B=32, N=16384, H=768, W=1024. rdepth layout [B][N][3] = (row, col, d) f32.

#define TPB 256

__global__ __launch_bounds__(TPB) void depthloss_pass1(
    const float* __restrict__ img,        // [B*H*W]
    const float4* __restrict__ rdepth4,   // B*N*3/4 float4s
    float2* __restrict__ partials,        // [gridDim.x]
    int N, int HW, int W, int nelem)
{
    int tid = blockIdx.x * blockDim.x + threadIdx.x;
    int e0 = tid * 4;                     // first of 4 elements for this thread

    float loss = 0.f;
    float cnt  = 0.f;

    if (e0 < nelem) {
        int b = e0 / N;                   // group of 4 never crosses b (N % 4 == 0)
        const float* base = img + (long)b * HW;

        // 4 elements = 12 floats = 3 aligned float4 loads
        float4 f0 = rdepth4[tid * 3 + 0];
        float4 f1 = rdepth4[tid * 3 + 1];
        float4 f2 = rdepth4[tid * 3 + 2];

        float r[4] = {f0.x, f0.w, f1.z, f2.y};
        float c[4] = {f0.y, f1.x, f1.w, f2.z};
        float d[4] = {f0.z, f1.y, f2.x, f2.w};

        #pragma unroll
        for (int k = 0; k < 4; ++k) {
            if (d[k] > 0.f) {
                int ri = (int)r[k];
                int ci = (int)c[k];
                float v = base[ri * W + ci];
                loss += fabsf(v - d[k]);
                cnt  += 1.f;
            }
        }
    }

    // 64-lane wave reduction
    #pragma unroll
    for (int off = 32; off > 0; off >>= 1) {
        loss += __shfl_down(loss, off);
        cnt  += __shfl_down(cnt,  off);
    }

    __shared__ float2 lds[TPB / 64];
    int lane = threadIdx.x & 63;
    int wid  = threadIdx.x >> 6;
    if (lane == 0) lds[wid] = make_float2(loss, cnt);
    __syncthreads();

    if (threadIdx.x == 0) {
        float L = 0.f, C = 0.f;
        #pragma unroll
        for (int w = 0; w < TPB / 64; ++w) { L += lds[w].x; C += lds[w].y; }
        partials[blockIdx.x] = make_float2(L, C);
    }
}

__global__ __launch_bounds__(512) void depthloss_pass2(
    const float2* __restrict__ partials, float* __restrict__ out, int nb)
{
    int t = threadIdx.x;
    float L = 0.f, C = 0.f;
    if (t < nb) { float2 p = partials[t]; L = p.x; C = p.y; }

    #pragma unroll
    for (int off = 32; off > 0; off >>= 1) {
        L += __shfl_down(L, off);
        C += __shfl_down(C, off);
    }

    __shared__ float2 lds[8];
    int lane = t & 63;
    int wid  = t >> 6;
    if (lane == 0) lds[wid] = make_float2(L, C);
    __syncthreads();

    if (t == 0) {
        float l = 0.f, c = 0.f;
        #pragma unroll
        for (int w = 0; w < 8; ++w) { l += lds[w].x; c += lds[w].y; }
        out[0] = (c > 0.f) ? (l / c) : 0.f;
    }
}

extern "C" void kernel_launch(void* const* d_in, const int* in_sizes, int n_in,
                              void* d_out, int out_size, void* d_ws, size_t ws_size,
                              hipStream_t stream) {
    const float* img    = (const float*)d_in[0];   // (B,1,H,W) f32
    const float* rdepth = (const float*)d_in[1];   // (B,N,3)  f32
    float* out = (float*)d_out;

    const int N  = 16384;
    const int H  = 768;
    const int W  = 1024;
    const int HW = H * W;

    int nelem    = in_sizes[1] / 3;                // B*N = 524288
    int nthreads = nelem / 4;                      // 131072
    int nblocks  = (nthreads + TPB - 1) / TPB;     // 512

    float2* partials = (float2*)d_ws;              // 512 * 8B = 4 KB

    depthloss_pass1<<<nblocks, TPB, 0, stream>>>(
        img, (const float4*)rdepth, partials, N, HW, W, nelem);
    depthloss_pass2<<<1, 512, 0, stream>>>(partials, out, nblocks);
}